// Round 1
// baseline (2356.512 us; speedup 1.0000x reference)
//
#include <hip/hip_runtime.h>
#include <hip/hip_bf16.h>
#include <math.h>

// Problem constants
#define BB    4
#define TT    1024
#define EE    256
#define HIDD  256
#define LLUT  8
#define HGT   384
#define WID   384
#define HWPX  147456      // 384*384
#define GSZ   33
#define G3    35937       // 33^3
#define NCOL  862488      // L*3*G3

__device__ __forceinline__ float gelu_f(float x) {
    // exact gelu: x * 0.5 * (1 + erf(x/sqrt(2)))
    return 0.5f * x * (1.0f + erff(x * 0.70710678f));
}

// ---------------------------------------------------------------------------
// K1: fused token head. One block per batch b (4 blocks, 256 threads).
//   tf0 = mean_t emb[tokens]; tf2 = gelu(tf0@aw1+ab1)@aw2+ab2
//   h3 = gelu(tf2@lw1+lb1)  (feeds big GEMM)
//   lw = softmax(gelu(tf2@gw1+gb1)@gw2+gb2)
// ---------------------------------------------------------------------------
__global__ __launch_bounds__(256) void mlp_head_kernel(
    const int* __restrict__ tokens, const float* __restrict__ emb,
    const float* __restrict__ aw1, const float* __restrict__ ab1,
    const float* __restrict__ aw2, const float* __restrict__ ab2,
    const float* __restrict__ lw1, const float* __restrict__ lb1,
    const float* __restrict__ gw1, const float* __restrict__ gb1,
    const float* __restrict__ gw2, const float* __restrict__ gb2,
    float* __restrict__ h3_out, float* __restrict__ lw_out)
{
    const int b = blockIdx.x;
    const int tid = threadIdx.x;
    __shared__ float tf[256], h1[256], tf2s[256], h4[64], lg[8];

    // embedding mean
    float acc = 0.f;
    const int* tok = tokens + b * TT;
#pragma unroll 8
    for (int t = 0; t < TT; ++t) {
        int tk = tok[t];
        acc += emb[tk * EE + tid];
    }
    tf[tid] = acc * (1.0f / TT);
    __syncthreads();

    {   // h1 = gelu(tf @ aw1 + ab1)
        float s = ab1[tid];
        for (int k = 0; k < EE; ++k) s += tf[k] * aw1[k * HIDD + tid];
        h1[tid] = gelu_f(s);
    }
    __syncthreads();
    {   // tf2 = h1 @ aw2 + ab2
        float s = ab2[tid];
        for (int k = 0; k < HIDD; ++k) s += h1[k] * aw2[k * HIDD + tid];
        tf2s[tid] = s;
    }
    __syncthreads();
    {   // h3 = gelu(tf2 @ lw1 + lb1)
        float s = lb1[tid];
        for (int k = 0; k < HIDD; ++k) s += tf2s[k] * lw1[k * HIDD + tid];
        h3_out[b * HIDD + tid] = gelu_f(s);
    }
    // weight-gate path
    if (tid < 64) {
        float s = gb1[tid];
        for (int k = 0; k < HIDD; ++k) s += tf2s[k] * gw1[k * 64 + tid];
        h4[tid] = gelu_f(s);
    }
    __syncthreads();
    if (tid < LLUT) {
        float s = gb2[tid];
        for (int k = 0; k < 64; ++k) s += h4[k] * gw2[k * LLUT + tid];
        lg[tid] = s;
    }
    __syncthreads();
    if (tid == 0) {
        float m = lg[0];
        for (int i = 1; i < LLUT; ++i) m = fmaxf(m, lg[i]);
        float ssum = 0.f, ex[LLUT];
        for (int i = 0; i < LLUT; ++i) { ex[i] = expf(lg[i] - m); ssum += ex[i]; }
        for (int i = 0; i < LLUT; ++i) lw_out[b * LLUT + i] = ex[i] / ssum;
    }
}

// ---------------------------------------------------------------------------
// K2: big GEMM  lut_params[b, col] = sum_k h3[b,k]*w2[k,col] + b2[col]
// Thread handles 4 consecutive columns (float4), all 4 batches.
// Memory-bound: streams 883 MB of w2 once, coalesced dwordx4.
// ---------------------------------------------------------------------------
__global__ __launch_bounds__(256) void lut_gemm_kernel(
    const float* __restrict__ h3, const float* __restrict__ w2,
    const float* __restrict__ b2, float* __restrict__ lp)
{
    __shared__ float h[BB * HIDD];
    const int tid = threadIdx.x;
    for (int i = tid; i < BB * HIDD; i += 256) h[i] = h3[i];
    __syncthreads();

    const long col = ((long)blockIdx.x * 256 + tid) * 4;
    if (col >= NCOL) return;

    const float4 bias = *(const float4*)(b2 + col);
    float4 a0 = bias, a1 = bias, a2 = bias, a3 = bias;
    const float* wp = w2 + col;
#pragma unroll 4
    for (int k = 0; k < HIDD; ++k) {
        float4 w = *(const float4*)(wp + (long)k * NCOL);
        float h0 = h[k], h1v = h[HIDD + k], h2 = h[2 * HIDD + k], h3v = h[3 * HIDD + k];
        a0.x += h0 * w.x;  a0.y += h0 * w.y;  a0.z += h0 * w.z;  a0.w += h0 * w.w;
        a1.x += h1v * w.x; a1.y += h1v * w.y; a1.z += h1v * w.z; a1.w += h1v * w.w;
        a2.x += h2 * w.x;  a2.y += h2 * w.y;  a2.z += h2 * w.z;  a2.w += h2 * w.w;
        a3.x += h3v * w.x; a3.y += h3v * w.y; a3.z += h3v * w.z; a3.w += h3v * w.w;
    }
    *(float4*)(lp + 0L * NCOL + col) = a0;
    *(float4*)(lp + 1L * NCOL + col) = a1;
    *(float4*)(lp + 2L * NCOL + col) = a2;
    *(float4*)(lp + 3L * NCOL + col) = a3;
}

// ---------------------------------------------------------------------------
// K3: combine 8 LUTs with softmax weights into one 3-channel LUT per batch.
//   clut[b,c,v] = sum_l lw[b,l] * lp[b, (l*3+c)*G3 + v]
// (einsum commutes with the gather since idx is channel-independent)
// ---------------------------------------------------------------------------
__global__ __launch_bounds__(256) void combine_kernel(
    const float* __restrict__ lp, const float* __restrict__ lwv,
    float* __restrict__ clut)
{
    const int v = blockIdx.x * 256 + threadIdx.x;
    const int b = blockIdx.y;
    if (v >= G3) return;
    float w[LLUT];
#pragma unroll
    for (int l = 0; l < LLUT; ++l) w[l] = lwv[b * LLUT + l];
#pragma unroll
    for (int c = 0; c < 3; ++c) {
        float s = 0.f;
#pragma unroll
        for (int l = 0; l < LLUT; ++l)
            s += w[l] * lp[(long)b * NCOL + (long)(l * 3 + c) * G3 + v];
        clut[(long)(b * 3 + c) * G3 + v] = s;
    }
}

// ---------------------------------------------------------------------------
// K4: trilinear-interpolate the combined LUT over recon -> fused (B,3,H,W)
// ---------------------------------------------------------------------------
__global__ __launch_bounds__(256) void applylut_kernel(
    const float* __restrict__ clut, const float* __restrict__ recon,
    float* __restrict__ fused)
{
    const int p = blockIdx.x * 256 + threadIdx.x;
    const int b = blockIdx.y;
    if (p >= HWPX) return;
    const float* rc = recon + (long)b * 3 * HWPX;
    float cr = fminf(fmaxf(rc[p] * 32.f, 0.f), 32.f);
    float cg = fminf(fmaxf(rc[HWPX + p] * 32.f, 0.f), 32.f);
    float cb = fminf(fmaxf(rc[2 * HWPX + p] * 32.f, 0.f), 32.f);
    float fr = fminf(floorf(cr), 31.f);
    float fg = fminf(floorf(cg), 31.f);
    float fb = fminf(floorf(cb), 31.f);
    float tr = cr - fr, tg = cg - fg, tb_ = cb - fb;
    int idx = (((int)fr * GSZ + (int)fg) * GSZ + (int)fb);
#pragma unroll
    for (int c = 0; c < 3; ++c) {
        const float* lut = clut + (long)(b * 3 + c) * G3;
        float v000 = lut[idx],            v001 = lut[idx + 1];
        float v010 = lut[idx + GSZ],      v011 = lut[idx + GSZ + 1];
        float v100 = lut[idx + GSZ*GSZ],        v101 = lut[idx + GSZ*GSZ + 1];
        float v110 = lut[idx + GSZ*GSZ + GSZ],  v111 = lut[idx + GSZ*GSZ + GSZ + 1];
        float c00 = v000 + (v001 - v000) * tb_;
        float c01 = v010 + (v011 - v010) * tb_;
        float c10 = v100 + (v101 - v100) * tb_;
        float c11 = v110 + (v111 - v110) * tb_;
        float c0 = c00 + (c01 - c00) * tg;
        float c1 = c10 + (c11 - c10) * tg;
        fused[(long)(b * 3 + c) * HWPX + p] = c0 + (c1 - c0) * tr;
    }
}

// ---------------------------------------------------------------------------
// K5: direct 3x3 SAME conv, NCHW. Thread = one pixel, all COUT channels.
// Weights staged in LDS (broadcast reads). Optional BN scale/shift, residual
// add (before gelu), gelu. CIN==6 reads concat(in0[3ch], in1[3ch]).
// ---------------------------------------------------------------------------
template <int CIN, int COUT, bool HAS_BN, bool HAS_GELU, bool HAS_RES>
__global__ __launch_bounds__(256) void conv3x3_kernel(
    const float* __restrict__ in0, const float* __restrict__ in1,
    const float* __restrict__ wgt, const float* __restrict__ bias,
    const float* __restrict__ bn_g, const float* __restrict__ bn_bt,
    const float* __restrict__ res, float* __restrict__ out)
{
    __shared__ float wl[COUT * CIN * 9];
    const int tid = threadIdx.x;
    for (int i = tid; i < COUT * CIN * 9; i += 256) wl[i] = wgt[i];
    __syncthreads();

    const int p = blockIdx.x * 256 + tid;
    const int b = blockIdx.y;
    if (p >= HWPX) return;
    const int hh = p / WID, ww = p - hh * WID;

    float acc[COUT];
#pragma unroll
    for (int o = 0; o < COUT; ++o) acc[o] = bias[o];

    for (int ci = 0; ci < CIN; ++ci) {
        const float* ip;
        if (CIN == 6)
            ip = (ci < 3) ? (in0 + (long)(b * 3 + ci) * HWPX)
                          : (in1 + (long)(b * 3 + (ci - 3)) * HWPX);
        else
            ip = in0 + (long)(b * CIN + ci) * HWPX;
        float x[9];
#pragma unroll
        for (int dh = 0; dh < 3; ++dh) {
            int hs = hh + dh - 1;
            bool hok = (hs >= 0) && (hs < HGT);
#pragma unroll
            for (int dw = 0; dw < 3; ++dw) {
                int wsx = ww + dw - 1;
                bool ok = hok && (wsx >= 0) && (wsx < WID);
                x[dh * 3 + dw] = ok ? ip[hs * WID + wsx] : 0.f;
            }
        }
#pragma unroll
        for (int o = 0; o < COUT; ++o) {
            const float* wv = &wl[(o * CIN + ci) * 9];
            float s = acc[o];
#pragma unroll
            for (int k = 0; k < 9; ++k) s += x[k] * wv[k];
            acc[o] = s;
        }
    }

    float* op = out + (long)b * COUT * HWPX + p;
    const float* rp = HAS_RES ? (res + (long)b * COUT * HWPX + p) : nullptr;
#pragma unroll
    for (int o = 0; o < COUT; ++o) {
        float v = acc[o];
        if (HAS_BN) v = v * (bn_g[o] * 0.9999950000375f) + bn_bt[o];  // g*(1+1e-5)^-0.5
        if (HAS_RES) v += rp[(long)o * HWPX];
        if (HAS_GELU) v = gelu_f(v);
        op[(long)o * HWPX] = v;
    }
}

// ---------------------------------------------------------------------------
extern "C" void kernel_launch(void* const* d_in, const int* in_sizes, int n_in,
                              void* d_out, int out_size, void* d_ws, size_t ws_size,
                              hipStream_t stream)
{
    const int*   tokens  = (const int*)d_in[0];
    const float* img     = (const float*)d_in[1];
    const float* recon   = (const float*)d_in[2];
    const float* emb     = (const float*)d_in[3];
    const float* agg_w1  = (const float*)d_in[4];
    const float* agg_b1  = (const float*)d_in[5];
    const float* agg_w2  = (const float*)d_in[6];
    const float* agg_b2  = (const float*)d_in[7];
    const float* lut_w1  = (const float*)d_in[8];
    const float* lut_b1  = (const float*)d_in[9];
    const float* lut_w2  = (const float*)d_in[10];
    const float* lut_b2  = (const float*)d_in[11];
    const float* wg_w1   = (const float*)d_in[12];
    const float* wg_b1   = (const float*)d_in[13];
    const float* wg_w2   = (const float*)d_in[14];
    const float* wg_b2   = (const float*)d_in[15];
    const float* rp_cin_w = (const float*)d_in[16];
    const float* rp_cin_b = (const float*)d_in[17];
    const float* rp_rbA_w = (const float*)d_in[18];
    const float* rp_rbA_b = (const float*)d_in[19];
    const float* rp_rbA_g = (const float*)d_in[20];
    const float* rp_rbA_bt= (const float*)d_in[21];
    const float* rp_rbB_w = (const float*)d_in[22];
    const float* rp_rbB_b = (const float*)d_in[23];
    const float* rp_rbB_g = (const float*)d_in[24];
    const float* rp_rbB_bt= (const float*)d_in[25];
    const float* rp_cout_w= (const float*)d_in[26];
    const float* rp_cout_b= (const float*)d_in[27];
    const float* fu_cin_w = (const float*)d_in[28];
    const float* fu_cin_b = (const float*)d_in[29];
    const float* fu_rbA_w = (const float*)d_in[30];
    const float* fu_rbA_b = (const float*)d_in[31];
    const float* fu_rbA_g = (const float*)d_in[32];
    const float* fu_rbA_bt= (const float*)d_in[33];
    const float* fu_rbB_w = (const float*)d_in[34];
    const float* fu_rbB_b = (const float*)d_in[35];
    const float* fu_rbB_g = (const float*)d_in[36];
    const float* fu_rbB_bt= (const float*)d_in[37];
    const float* fu_cout_w= (const float*)d_in[38];
    const float* fu_cout_b= (const float*)d_in[39];

    float* ws = (float*)d_ws;
    // lifetime-based layout (floats); lp and proc3 alias t1 (disjoint lifetimes)
    float* h3    = ws;                 // 1024
    float* lwv   = ws + 1024;          // 32
    float* clut  = ws + 2048;          // 431244
    float* fused = ws + 435200;        // 1769472
    float* t0    = ws + 2204672;       // 18874368 (4*32*HW)
    float* t1    = ws + 21079040;      // 18874368
    float* lp    = t1;                 // 3449952, dead after combine_kernel
    float* proc3 = t1;                 // 1769472, live rp_cout -> fu_cin
    float* outp  = (float*)d_out;

    // token head
    mlp_head_kernel<<<dim3(BB), dim3(256), 0, stream>>>(
        tokens, emb, agg_w1, agg_b1, agg_w2, agg_b2,
        lut_w1, lut_b1, wg_w1, wg_b1, wg_w2, wg_b2, h3, lwv);

    // big LUT GEMM (HBM-bound anchor: 883 MB weight stream)
    lut_gemm_kernel<<<dim3((NCOL / 4 + 255) / 256), dim3(256), 0, stream>>>(
        h3, lut_w2, lut_b2, lp);

    // fold softmax einsum into a single 3-ch LUT per batch
    combine_kernel<<<dim3((G3 + 255) / 256, BB), dim3(256), 0, stream>>>(lp, lwv, clut);

    // trilinear apply -> fused
    applylut_kernel<<<dim3(HWPX / 256, BB), dim3(256), 0, stream>>>(clut, recon, fused);

    const dim3 cgrid(HWPX / 256, BB), cblk(256);
    // proc branch: img -> t0 -> t1 -> t0(inplace res) -> proc3
    conv3x3_kernel<3, 32, false, true, false><<<cgrid, cblk, 0, stream>>>(
        img, nullptr, rp_cin_w, rp_cin_b, nullptr, nullptr, nullptr, t0);
    conv3x3_kernel<32, 32, true, true, false><<<cgrid, cblk, 0, stream>>>(
        t0, nullptr, rp_rbA_w, rp_rbA_b, rp_rbA_g, rp_rbA_bt, nullptr, t1);
    conv3x3_kernel<32, 32, true, true, true><<<cgrid, cblk, 0, stream>>>(
        t1, nullptr, rp_rbB_w, rp_rbB_b, rp_rbB_g, rp_rbB_bt, t0, t0);
    conv3x3_kernel<32, 3, false, false, false><<<cgrid, cblk, 0, stream>>>(
        t0, nullptr, rp_cout_w, rp_cout_b, nullptr, nullptr, nullptr, proc3);

    // fuse branch: concat(fused, proc3) -> t0 -> t1 -> t0 -> d_out (+img)
    conv3x3_kernel<6, 32, false, true, false><<<cgrid, cblk, 0, stream>>>(
        fused, proc3, fu_cin_w, fu_cin_b, nullptr, nullptr, nullptr, t0);
    conv3x3_kernel<32, 32, true, true, false><<<cgrid, cblk, 0, stream>>>(
        t0, nullptr, fu_rbA_w, fu_rbA_b, fu_rbA_g, fu_rbA_bt, nullptr, t1);
    conv3x3_kernel<32, 32, true, true, true><<<cgrid, cblk, 0, stream>>>(
        t1, nullptr, fu_rbB_w, fu_rbB_b, fu_rbB_g, fu_rbB_bt, t0, t0);
    conv3x3_kernel<32, 3, false, false, true><<<cgrid, cblk, 0, stream>>>(
        t0, nullptr, fu_cout_w, fu_cout_b, nullptr, nullptr, img, outp);
}

// Round 2
// 1503.524 us; speedup vs baseline: 1.5673x; 1.5673x over previous
//
#include <hip/hip_runtime.h>
#include <hip/hip_bf16.h>
#include <math.h>

// Problem constants
#define BB    4
#define TT    1024
#define EE    256
#define HIDD  256
#define LLUT  8
#define HGT   384
#define WID   384
#define HWPX  147456      // 384*384
#define GSZ   33
#define G3    35937       // 33^3
#define NCOL  862488      // L*3*G3

__device__ __forceinline__ float gelu_f(float x) {
    // exact gelu: x * 0.5 * (1 + erf(x/sqrt(2)))
    return 0.5f * x * (1.0f + erff(x * 0.70710678f));
}

// ---------------------------------------------------------------------------
// K0: parallel embedding-mean partial sums. grid (8, B). partial[b][s][e]
// ---------------------------------------------------------------------------
__global__ __launch_bounds__(256) void emb_partial_kernel(
    const int* __restrict__ tokens, const float* __restrict__ emb,
    float* __restrict__ partial)
{
    const int s = blockIdx.x, b = blockIdx.y, tid = threadIdx.x;
    const int* tok = tokens + b * TT + s * 128;
    float acc = 0.f;
#pragma unroll 8
    for (int t = 0; t < 128; ++t) acc += emb[tok[t] * EE + tid];
    partial[(b * 8 + s) * EE + tid] = acc;
}

// ---------------------------------------------------------------------------
// K1: fused token head. One block per batch b (4 blocks, 256 threads).
// ---------------------------------------------------------------------------
__global__ __launch_bounds__(256) void mlp_head_kernel(
    const float* __restrict__ partial,
    const float* __restrict__ aw1, const float* __restrict__ ab1,
    const float* __restrict__ aw2, const float* __restrict__ ab2,
    const float* __restrict__ lw1, const float* __restrict__ lb1,
    const float* __restrict__ gw1, const float* __restrict__ gb1,
    const float* __restrict__ gw2, const float* __restrict__ gb2,
    float* __restrict__ h3_out, float* __restrict__ lw_out)
{
    const int b = blockIdx.x;
    const int tid = threadIdx.x;
    __shared__ float tf[256], h1[256], tf2s[256], h4[64], lg[8];

    // embedding mean from partials
    float acc = 0.f;
#pragma unroll
    for (int s = 0; s < 8; ++s) acc += partial[(b * 8 + s) * EE + tid];
    tf[tid] = acc * (1.0f / TT);
    __syncthreads();

    {   // h1 = gelu(tf @ aw1 + ab1)
        float s = ab1[tid];
        for (int k = 0; k < EE; ++k) s += tf[k] * aw1[k * HIDD + tid];
        h1[tid] = gelu_f(s);
    }
    __syncthreads();
    {   // tf2 = h1 @ aw2 + ab2
        float s = ab2[tid];
        for (int k = 0; k < HIDD; ++k) s += h1[k] * aw2[k * HIDD + tid];
        tf2s[tid] = s;
    }
    __syncthreads();
    {   // h3 = gelu(tf2 @ lw1 + lb1)
        float s = lb1[tid];
        for (int k = 0; k < HIDD; ++k) s += tf2s[k] * lw1[k * HIDD + tid];
        h3_out[b * HIDD + tid] = gelu_f(s);
    }
    // weight-gate path
    if (tid < 64) {
        float s = gb1[tid];
        for (int k = 0; k < HIDD; ++k) s += tf2s[k] * gw1[k * 64 + tid];
        h4[tid] = gelu_f(s);
    }
    __syncthreads();
    if (tid < LLUT) {
        float s = gb2[tid];
        for (int k = 0; k < 64; ++k) s += h4[k] * gw2[k * LLUT + tid];
        lg[tid] = s;
    }
    __syncthreads();
    if (tid == 0) {
        float m = lg[0];
        for (int i = 1; i < LLUT; ++i) m = fmaxf(m, lg[i]);
        float ssum = 0.f, ex[LLUT];
        for (int i = 0; i < LLUT; ++i) { ex[i] = expf(lg[i] - m); ssum += ex[i]; }
        for (int i = 0; i < LLUT; ++i) lw_out[b * LLUT + i] = ex[i] / ssum;
    }
}

// ---------------------------------------------------------------------------
// K2: big GEMM  lut_params[b, col] = sum_k h3[b,k]*w2[k,col] + b2[col]
// Streams 883 MB of w2 once, coalesced dwordx4. HBM-bound floor ~140 us.
// ---------------------------------------------------------------------------
__global__ __launch_bounds__(256) void lut_gemm_kernel(
    const float* __restrict__ h3, const float* __restrict__ w2,
    const float* __restrict__ b2, float* __restrict__ lp)
{
    __shared__ float h[BB * HIDD];
    const int tid = threadIdx.x;
    for (int i = tid; i < BB * HIDD; i += 256) h[i] = h3[i];
    __syncthreads();

    const long col = ((long)blockIdx.x * 256 + tid) * 4;
    if (col >= NCOL) return;

    const float4 bias = *(const float4*)(b2 + col);
    float4 a0 = bias, a1 = bias, a2 = bias, a3 = bias;
    const float* wp = w2 + col;
#pragma unroll 4
    for (int k = 0; k < HIDD; ++k) {
        float4 w = *(const float4*)(wp + (long)k * NCOL);
        float h0 = h[k], h1v = h[HIDD + k], h2 = h[2 * HIDD + k], h3v = h[3 * HIDD + k];
        a0.x += h0 * w.x;  a0.y += h0 * w.y;  a0.z += h0 * w.z;  a0.w += h0 * w.w;
        a1.x += h1v * w.x; a1.y += h1v * w.y; a1.z += h1v * w.z; a1.w += h1v * w.w;
        a2.x += h2 * w.x;  a2.y += h2 * w.y;  a2.z += h2 * w.z;  a2.w += h2 * w.w;
        a3.x += h3v * w.x; a3.y += h3v * w.y; a3.z += h3v * w.z; a3.w += h3v * w.w;
    }
    *(float4*)(lp + 0L * NCOL + col) = a0;
    *(float4*)(lp + 1L * NCOL + col) = a1;
    *(float4*)(lp + 2L * NCOL + col) = a2;
    *(float4*)(lp + 3L * NCOL + col) = a3;
}

// ---------------------------------------------------------------------------
// K3: combine 8 LUTs with softmax weights into one 3-channel LUT per batch.
// ---------------------------------------------------------------------------
__global__ __launch_bounds__(256) void combine_kernel(
    const float* __restrict__ lp, const float* __restrict__ lwv,
    float* __restrict__ clut)
{
    const int v = blockIdx.x * 256 + threadIdx.x;
    const int b = blockIdx.y;
    if (v >= G3) return;
    float w[LLUT];
#pragma unroll
    for (int l = 0; l < LLUT; ++l) w[l] = lwv[b * LLUT + l];
#pragma unroll
    for (int c = 0; c < 3; ++c) {
        float s = 0.f;
#pragma unroll
        for (int l = 0; l < LLUT; ++l)
            s += w[l] * lp[(long)b * NCOL + (long)(l * 3 + c) * G3 + v];
        clut[(long)(b * 3 + c) * G3 + v] = s;
    }
}

// ---------------------------------------------------------------------------
// K4: trilinear-interpolate the combined LUT over recon -> fused (B,3,H,W)
// ---------------------------------------------------------------------------
__global__ __launch_bounds__(256) void applylut_kernel(
    const float* __restrict__ clut, const float* __restrict__ recon,
    float* __restrict__ fused)
{
    const int p = blockIdx.x * 256 + threadIdx.x;
    const int b = blockIdx.y;
    if (p >= HWPX) return;
    const float* rc = recon + (long)b * 3 * HWPX;
    float cr = fminf(fmaxf(rc[p] * 32.f, 0.f), 32.f);
    float cg = fminf(fmaxf(rc[HWPX + p] * 32.f, 0.f), 32.f);
    float cb = fminf(fmaxf(rc[2 * HWPX + p] * 32.f, 0.f), 32.f);
    float fr = fminf(floorf(cr), 31.f);
    float fg = fminf(floorf(cg), 31.f);
    float fb = fminf(floorf(cb), 31.f);
    float tr = cr - fr, tg = cg - fg, tb_ = cb - fb;
    int idx = (((int)fr * GSZ + (int)fg) * GSZ + (int)fb);
#pragma unroll
    for (int c = 0; c < 3; ++c) {
        const float* lut = clut + (long)(b * 3 + c) * G3;
        float v000 = lut[idx],            v001 = lut[idx + 1];
        float v010 = lut[idx + GSZ],      v011 = lut[idx + GSZ + 1];
        float v100 = lut[idx + GSZ*GSZ],        v101 = lut[idx + GSZ*GSZ + 1];
        float v110 = lut[idx + GSZ*GSZ + GSZ],  v111 = lut[idx + GSZ*GSZ + GSZ + 1];
        float c00 = v000 + (v001 - v000) * tb_;
        float c01 = v010 + (v011 - v010) * tb_;
        float c10 = v100 + (v101 - v100) * tb_;
        float c11 = v110 + (v111 - v110) * tb_;
        float c0 = c00 + (c01 - c00) * tg;
        float c1 = c10 + (c11 - c10) * tg;
        fused[(long)(b * 3 + c) * HWPX + p] = c0 + (c1 - c0) * tr;
    }
}

// ---------------------------------------------------------------------------
// K5 v2: direct 3x3 SAME conv, NCHW. Thread = 2 consecutive pixels (same row,
// p0 even & WID even), all COUT channels. Weights fetched via UNIFORM indices
// -> compiler emits s_load; every FMA sources its weight from an SGPR (no LDS,
// no vector weight loads). Window loads: 3x4 per ci, shared by both pixels.
// ---------------------------------------------------------------------------
template <int CIN, int COUT, bool HAS_BN, bool HAS_GELU, bool HAS_RES>
__global__ __launch_bounds__(256) void conv3x3_v2(
    const float* __restrict__ in0, const float* __restrict__ in1,
    const float* __restrict__ wgt, const float* __restrict__ bias,
    const float* __restrict__ bn_g, const float* __restrict__ bn_bt,
    const float* __restrict__ res, float* __restrict__ out)
{
    const int tid = threadIdx.x;
    const int p0 = (blockIdx.x * 256 + tid) * 2;
    const int b = blockIdx.y;
    const int hh = p0 / WID, ww = p0 - hh * WID;   // ww even => ww+1 same row

    float acc[COUT][2];
#pragma unroll
    for (int o = 0; o < COUT; ++o) { float bv = bias[o]; acc[o][0] = bv; acc[o][1] = bv; }

    const bool wlo = (ww > 0);
    const bool whi = (ww + 2 < WID);

    for (int ci = 0; ci < CIN; ++ci) {
        const float* ip;
        if (CIN == 6)
            ip = (ci < 3) ? (in0 + (long)(b * 3 + ci) * HWPX)
                          : (in1 + (long)(b * 3 + (ci - 3)) * HWPX);
        else
            ip = in0 + (long)(b * CIN + ci) * HWPX;

        float x[3][4];
#pragma unroll
        for (int dh = 0; dh < 3; ++dh) {
            const int hs = hh + dh - 1;
            const bool hok = (hs >= 0) && (hs < HGT);
            const float* rp_ = ip + hs * WID + ww;
            x[dh][0] = (hok && wlo) ? rp_[-1] : 0.f;
            x[dh][1] = hok ? rp_[0] : 0.f;
            x[dh][2] = hok ? rp_[1] : 0.f;
            x[dh][3] = (hok && whi) ? rp_[2] : 0.f;
        }
        // uniform weight pointer for this ci
        const float* wp = wgt + ci * 9;
#pragma unroll
        for (int o = 0; o < COUT; ++o) {
            const float* wv = wp + o * CIN * 9;   // uniform -> s_load
#pragma unroll
            for (int dh = 0; dh < 3; ++dh) {
#pragma unroll
                for (int dw = 0; dw < 3; ++dw) {
                    const float w = wv[dh * 3 + dw];
                    acc[o][0] += x[dh][dw]     * w;
                    acc[o][1] += x[dh][dw + 1] * w;
                }
            }
        }
    }

    float* op = out + (long)b * COUT * HWPX + p0;
    const float* rpt = HAS_RES ? (res + (long)b * COUT * HWPX + p0) : nullptr;
#pragma unroll
    for (int o = 0; o < COUT; ++o) {
        float v0 = acc[o][0], v1 = acc[o][1];
        if (HAS_BN) {
            const float sg = bn_g[o] * 0.9999950000375f;   // g*(1+1e-5)^-0.5
            const float sb = bn_bt[o];
            v0 = v0 * sg + sb;  v1 = v1 * sg + sb;
        }
        if (HAS_RES) {
            float2 rv = *(const float2*)(rpt + (long)o * HWPX);
            v0 += rv.x;  v1 += rv.y;
        }
        if (HAS_GELU) { v0 = gelu_f(v0); v1 = gelu_f(v1); }
        float2 ov; ov.x = v0; ov.y = v1;
        *(float2*)(op + (long)o * HWPX) = ov;
    }
}

// ---------------------------------------------------------------------------
extern "C" void kernel_launch(void* const* d_in, const int* in_sizes, int n_in,
                              void* d_out, int out_size, void* d_ws, size_t ws_size,
                              hipStream_t stream)
{
    const int*   tokens  = (const int*)d_in[0];
    const float* img     = (const float*)d_in[1];
    const float* recon   = (const float*)d_in[2];
    const float* emb     = (const float*)d_in[3];
    const float* agg_w1  = (const float*)d_in[4];
    const float* agg_b1  = (const float*)d_in[5];
    const float* agg_w2  = (const float*)d_in[6];
    const float* agg_b2  = (const float*)d_in[7];
    const float* lut_w1  = (const float*)d_in[8];
    const float* lut_b1  = (const float*)d_in[9];
    const float* lut_w2  = (const float*)d_in[10];
    const float* lut_b2  = (const float*)d_in[11];
    const float* wg_w1   = (const float*)d_in[12];
    const float* wg_b1   = (const float*)d_in[13];
    const float* wg_w2   = (const float*)d_in[14];
    const float* wg_b2   = (const float*)d_in[15];
    const float* rp_cin_w = (const float*)d_in[16];
    const float* rp_cin_b = (const float*)d_in[17];
    const float* rp_rbA_w = (const float*)d_in[18];
    const float* rp_rbA_b = (const float*)d_in[19];
    const float* rp_rbA_g = (const float*)d_in[20];
    const float* rp_rbA_bt= (const float*)d_in[21];
    const float* rp_rbB_w = (const float*)d_in[22];
    const float* rp_rbB_b = (const float*)d_in[23];
    const float* rp_rbB_g = (const float*)d_in[24];
    const float* rp_rbB_bt= (const float*)d_in[25];
    const float* rp_cout_w= (const float*)d_in[26];
    const float* rp_cout_b= (const float*)d_in[27];
    const float* fu_cin_w = (const float*)d_in[28];
    const float* fu_cin_b = (const float*)d_in[29];
    const float* fu_rbA_w = (const float*)d_in[30];
    const float* fu_rbA_b = (const float*)d_in[31];
    const float* fu_rbA_g = (const float*)d_in[32];
    const float* fu_rbA_bt= (const float*)d_in[33];
    const float* fu_rbB_w = (const float*)d_in[34];
    const float* fu_rbB_b = (const float*)d_in[35];
    const float* fu_rbB_g = (const float*)d_in[36];
    const float* fu_rbB_bt= (const float*)d_in[37];
    const float* fu_cout_w= (const float*)d_in[38];
    const float* fu_cout_b= (const float*)d_in[39];

    float* ws = (float*)d_ws;
    // lifetime-based layout (floats); lp and proc3 alias t1 (disjoint lifetimes)
    float* h3      = ws;                 // 1024
    float* lwv     = ws + 1024;          // 32
    float* partial = ws + 2048;          // 8192
    float* clut    = ws + 16384;         // 431244
    float* fused   = ws + 458752;        // 1769472
    float* t0      = ws + 2228224;       // 18874368 (4*32*HW)
    float* t1      = ws + 21102592;      // 18874368
    float* lp      = t1;                 // 3449952, dead after combine_kernel
    float* proc3   = t1;                 // 1769472, live rp_cout -> fu_cin
    float* outp    = (float*)d_out;

    // token head (two-phase for gather parallelism)
    emb_partial_kernel<<<dim3(8, BB), dim3(256), 0, stream>>>(tokens, emb, partial);
    mlp_head_kernel<<<dim3(BB), dim3(256), 0, stream>>>(
        partial, agg_w1, agg_b1, agg_w2, agg_b2,
        lut_w1, lut_b1, wg_w1, wg_b1, wg_w2, wg_b2, h3, lwv);

    // big LUT GEMM (HBM-bound anchor: 883 MB weight stream)
    lut_gemm_kernel<<<dim3((NCOL / 4 + 255) / 256), dim3(256), 0, stream>>>(
        h3, lut_w2, lut_b2, lp);

    // fold softmax einsum into a single 3-ch LUT per batch
    combine_kernel<<<dim3((G3 + 255) / 256, BB), dim3(256), 0, stream>>>(lp, lwv, clut);

    // trilinear apply -> fused
    applylut_kernel<<<dim3(HWPX / 256, BB), dim3(256), 0, stream>>>(clut, recon, fused);

    const dim3 cgrid(HWPX / 512, BB), cblk(256);   // 2 px/thread
    // proc branch: img -> t0 -> t1 -> t0(inplace res) -> proc3
    conv3x3_v2<3, 32, false, true, false><<<cgrid, cblk, 0, stream>>>(
        img, nullptr, rp_cin_w, rp_cin_b, nullptr, nullptr, nullptr, t0);
    conv3x3_v2<32, 32, true, true, false><<<cgrid, cblk, 0, stream>>>(
        t0, nullptr, rp_rbA_w, rp_rbA_b, rp_rbA_g, rp_rbA_bt, nullptr, t1);
    conv3x3_v2<32, 32, true, true, true><<<cgrid, cblk, 0, stream>>>(
        t1, nullptr, rp_rbB_w, rp_rbB_b, rp_rbB_g, rp_rbB_bt, t0, t0);
    conv3x3_v2<32, 3, false, false, false><<<cgrid, cblk, 0, stream>>>(
        t0, nullptr, rp_cout_w, rp_cout_b, nullptr, nullptr, nullptr, proc3);

    // fuse branch: concat(fused, proc3) -> t0 -> t1 -> t0 -> d_out (+img)
    conv3x3_v2<6, 32, false, true, false><<<cgrid, cblk, 0, stream>>>(
        fused, proc3, fu_cin_w, fu_cin_b, nullptr, nullptr, nullptr, t0);
    conv3x3_v2<32, 32, true, true, false><<<cgrid, cblk, 0, stream>>>(
        t0, nullptr, fu_rbA_w, fu_rbA_b, fu_rbA_g, fu_rbA_bt, nullptr, t1);
    conv3x3_v2<32, 32, true, true, true><<<cgrid, cblk, 0, stream>>>(
        t1, nullptr, fu_rbB_w, fu_rbB_b, fu_rbB_g, fu_rbB_bt, t0, t0);
    conv3x3_v2<32, 3, false, false, true><<<cgrid, cblk, 0, stream>>>(
        t0, nullptr, fu_cout_w, fu_cout_b, nullptr, nullptr, img, outp);
}

// Round 3
// 624.939 us; speedup vs baseline: 3.7708x; 2.4059x over previous
//
#include <hip/hip_runtime.h>
#include <hip/hip_bf16.h>
#include <math.h>

// Problem constants
#define BB    4
#define TT    1024
#define EE    256
#define HIDD  256
#define LLUT  8
#define HGT   384
#define WID   384
#define HWPX  147456      // 384*384
#define GSZ   33
#define G3    35937       // 33^3
#define NCOL  862488      // L*3*G3

typedef __attribute__((ext_vector_type(8))) short bf16x8;   // 8 bf16 = 4 VGPRs
typedef __attribute__((ext_vector_type(4))) float f32x4;

// fast gelu (tanh form): max abs dev from exact erf-gelu ~1e-3, threshold 2e-2
__device__ __forceinline__ float gelu_f(float x) {
    float s = 1.5957691216057308f * x * (1.0f + 0.044715f * x * x);
    float e = __expf(s);
    return x - x / (e + 1.0f);   // x*sigmoid(s); safe at +-inf
}

__device__ __forceinline__ ushort f2bf(float x) {
    uint u = __float_as_uint(x);
    return (ushort)((u + 0x7FFFu + ((u >> 16) & 1u)) >> 16);   // RNE
}
__device__ __forceinline__ uint pack2bf(float a, float b) {
    return (uint)f2bf(a) | ((uint)f2bf(b) << 16);
}
__device__ __forceinline__ float bf2f_lo(uint u) { return __uint_as_float(u << 16); }
__device__ __forceinline__ float bf2f_hi(uint u) { return __uint_as_float(u & 0xFFFF0000u); }

// ---------------------------------------------------------------------------
// K0: embedding-mean partial sums. grid (32, B): 32 tokens per block.
// ---------------------------------------------------------------------------
__global__ __launch_bounds__(256) void emb_partial_kernel(
    const int* __restrict__ tokens, const float* __restrict__ emb,
    float* __restrict__ partial)
{
    const int s = blockIdx.x, b = blockIdx.y, tid = threadIdx.x;
    const int* tok = tokens + b * TT + s * 32;
    float acc = 0.f;
#pragma unroll 8
    for (int t = 0; t < 32; ++t) acc += emb[tok[t] * EE + tid];
    partial[(b * 32 + s) * EE + tid] = acc;
}

// ---------------------------------------------------------------------------
// K1: fused token head. One block per batch b.
// ---------------------------------------------------------------------------
__global__ __launch_bounds__(256) void mlp_head_kernel(
    const float* __restrict__ partial,
    const float* __restrict__ aw1, const float* __restrict__ ab1,
    const float* __restrict__ aw2, const float* __restrict__ ab2,
    const float* __restrict__ lw1, const float* __restrict__ lb1,
    const float* __restrict__ gw1, const float* __restrict__ gb1,
    const float* __restrict__ gw2, const float* __restrict__ gb2,
    float* __restrict__ h3_out, float* __restrict__ lw_out)
{
    const int b = blockIdx.x;
    const int tid = threadIdx.x;
    __shared__ float tf[256], h1[256], tf2s[256], h4[64], lg[8];

    float acc = 0.f;
#pragma unroll
    for (int s = 0; s < 32; ++s) acc += partial[(b * 32 + s) * EE + tid];
    tf[tid] = acc * (1.0f / TT);
    __syncthreads();

    {   float s = ab1[tid];
        for (int k = 0; k < EE; ++k) s += tf[k] * aw1[k * HIDD + tid];
        h1[tid] = gelu_f(s);
    }
    __syncthreads();
    {   float s = ab2[tid];
        for (int k = 0; k < HIDD; ++k) s += h1[k] * aw2[k * HIDD + tid];
        tf2s[tid] = s;
    }
    __syncthreads();
    {   float s = lb1[tid];
        for (int k = 0; k < HIDD; ++k) s += tf2s[k] * lw1[k * HIDD + tid];
        h3_out[b * HIDD + tid] = gelu_f(s);
    }
    if (tid < 64) {
        float s = gb1[tid];
        for (int k = 0; k < HIDD; ++k) s += tf2s[k] * gw1[k * 64 + tid];
        h4[tid] = gelu_f(s);
    }
    __syncthreads();
    if (tid < LLUT) {
        float s = gb2[tid];
        for (int k = 0; k < 64; ++k) s += h4[k] * gw2[k * LLUT + tid];
        lg[tid] = s;
    }
    __syncthreads();
    if (tid == 0) {
        float m = lg[0];
        for (int i = 1; i < LLUT; ++i) m = fmaxf(m, lg[i]);
        float ssum = 0.f, ex[LLUT];
        for (int i = 0; i < LLUT; ++i) { ex[i] = expf(lg[i] - m); ssum += ex[i]; }
        for (int i = 0; i < LLUT; ++i) lw_out[b * LLUT + i] = ex[i] / ssum;
    }
}

// ---------------------------------------------------------------------------
// K2: big GEMM. Streams 883 MB of w2 once; HBM-bound floor ~140 us.
// ---------------------------------------------------------------------------
__global__ __launch_bounds__(256) void lut_gemm_kernel(
    const float* __restrict__ h3, const float* __restrict__ w2,
    const float* __restrict__ b2, float* __restrict__ lp)
{
    __shared__ float h[BB * HIDD];
    const int tid = threadIdx.x;
    for (int i = tid; i < BB * HIDD; i += 256) h[i] = h3[i];
    __syncthreads();

    const long col = ((long)blockIdx.x * 256 + tid) * 4;
    if (col >= NCOL) return;

    const float4 bias = *(const float4*)(b2 + col);
    float4 a0 = bias, a1 = bias, a2 = bias, a3 = bias;
    const float* wp = w2 + col;
#pragma unroll 4
    for (int k = 0; k < HIDD; ++k) {
        float4 w = *(const float4*)(wp + (long)k * NCOL);
        float h0 = h[k], h1v = h[HIDD + k], h2 = h[2 * HIDD + k], h3v = h[3 * HIDD + k];
        a0.x += h0 * w.x;  a0.y += h0 * w.y;  a0.z += h0 * w.z;  a0.w += h0 * w.w;
        a1.x += h1v * w.x; a1.y += h1v * w.y; a1.z += h1v * w.z; a1.w += h1v * w.w;
        a2.x += h2 * w.x;  a2.y += h2 * w.y;  a2.z += h2 * w.z;  a2.w += h2 * w.w;
        a3.x += h3v * w.x; a3.y += h3v * w.y; a3.z += h3v * w.z; a3.w += h3v * w.w;
    }
    *(float4*)(lp + 0L * NCOL + col) = a0;
    *(float4*)(lp + 1L * NCOL + col) = a1;
    *(float4*)(lp + 2L * NCOL + col) = a2;
    *(float4*)(lp + 3L * NCOL + col) = a3;
}

// ---------------------------------------------------------------------------
// K3: combine 8 LUTs with softmax weights -> one 3-channel LUT per batch.
// ---------------------------------------------------------------------------
__global__ __launch_bounds__(256) void combine_kernel(
    const float* __restrict__ lp, const float* __restrict__ lwv,
    float* __restrict__ clut)
{
    const int v = blockIdx.x * 256 + threadIdx.x;
    const int b = blockIdx.y;
    if (v >= G3) return;
    float w[LLUT];
#pragma unroll
    for (int l = 0; l < LLUT; ++l) w[l] = lwv[b * LLUT + l];
#pragma unroll
    for (int c = 0; c < 3; ++c) {
        float s = 0.f;
#pragma unroll
        for (int l = 0; l < LLUT; ++l)
            s += w[l] * lp[(long)b * NCOL + (long)(l * 3 + c) * G3 + v];
        clut[(long)(b * 3 + c) * G3 + v] = s;
    }
}

// ---------------------------------------------------------------------------
// K4: trilinear LUT apply -> comb slots 0..2 (fp32, [px][8] layout)
// ---------------------------------------------------------------------------
__global__ __launch_bounds__(256) void applylut_kernel(
    const float* __restrict__ clut, const float* __restrict__ recon,
    float* __restrict__ comb)
{
    const int p = blockIdx.x * 256 + threadIdx.x;
    const int b = blockIdx.y;
    const float* rc = recon + (long)b * 3 * HWPX;
    float cr = fminf(fmaxf(rc[p] * 32.f, 0.f), 32.f);
    float cg = fminf(fmaxf(rc[HWPX + p] * 32.f, 0.f), 32.f);
    float cb = fminf(fmaxf(rc[2 * HWPX + p] * 32.f, 0.f), 32.f);
    float fr = fminf(floorf(cr), 31.f);
    float fg = fminf(floorf(cg), 31.f);
    float fb = fminf(floorf(cb), 31.f);
    float tr = cr - fr, tg = cg - fg, tb_ = cb - fb;
    int idx = (((int)fr * GSZ + (int)fg) * GSZ + (int)fb);
    float c[3];
#pragma unroll
    for (int ch = 0; ch < 3; ++ch) {
        const float* lut = clut + (long)(b * 3 + ch) * G3;
        float v000 = lut[idx],                  v001 = lut[idx + 1];
        float v010 = lut[idx + GSZ],            v011 = lut[idx + GSZ + 1];
        float v100 = lut[idx + GSZ * GSZ],      v101 = lut[idx + GSZ * GSZ + 1];
        float v110 = lut[idx + GSZ * GSZ + GSZ], v111 = lut[idx + GSZ * GSZ + GSZ + 1];
        float c00 = v000 + (v001 - v000) * tb_;
        float c01 = v010 + (v011 - v010) * tb_;
        float c10 = v100 + (v101 - v100) * tb_;
        float c11 = v110 + (v111 - v110) * tb_;
        float c0 = c00 + (c01 - c00) * tg;
        float c1 = c10 + (c11 - c10) * tg;
        c[ch] = c0 + (c1 - c0) * tr;
    }
    float4 r4; r4.x = c[0]; r4.y = c[1]; r4.z = c[2]; r4.w = 0.f;
    *(float4*)(comb + ((long)b * HWPX + p) * 8) = r4;
}

// ---------------------------------------------------------------------------
// K5: 3->32 conv (img fp32 NCHW -> act NHWC bf16), gelu. 2 px/thread.
// Weights via uniform indices -> SGPRs.
// ---------------------------------------------------------------------------
__global__ __launch_bounds__(256) void conv_in3_kernel(
    const float* __restrict__ img, const float* __restrict__ wgt,
    const float* __restrict__ bias, ushort* __restrict__ out)
{
    const int tid = threadIdx.x;
    const int p0 = (blockIdx.x * 256 + tid) * 2;
    const int b = blockIdx.y;
    const int hh = p0 / WID, ww = p0 - hh * WID;

    float acc[32][2];
#pragma unroll
    for (int o = 0; o < 32; ++o) { float bv = bias[o]; acc[o][0] = bv; acc[o][1] = bv; }

    const bool wlo = (ww > 0), whi = (ww + 2 < WID);
#pragma unroll
    for (int ci = 0; ci < 3; ++ci) {
        const float* ip = img + (long)(b * 3 + ci) * HWPX;
        float x[3][4];
#pragma unroll
        for (int dh = 0; dh < 3; ++dh) {
            const int hs = hh + dh - 1;
            const bool hok = (hs >= 0) && (hs < HGT);
            const float* rp_ = ip + hs * WID + ww;
            x[dh][0] = (hok && wlo) ? rp_[-1] : 0.f;
            x[dh][1] = hok ? rp_[0] : 0.f;
            x[dh][2] = hok ? rp_[1] : 0.f;
            x[dh][3] = (hok && whi) ? rp_[2] : 0.f;
        }
#pragma unroll
        for (int o = 0; o < 32; ++o) {
            const float* wv = wgt + o * 27 + ci * 9;   // uniform -> s_load
#pragma unroll
            for (int dh = 0; dh < 3; ++dh)
#pragma unroll
                for (int dw = 0; dw < 3; ++dw) {
                    const float w = wv[dh * 3 + dw];
                    acc[o][0] += x[dh][dw]     * w;
                    acc[o][1] += x[dh][dw + 1] * w;
                }
        }
    }

    ushort* op = out + ((long)b * HWPX + p0) * 32;
#pragma unroll
    for (int px = 0; px < 2; ++px) {
        uint u[16];
#pragma unroll
        for (int o2 = 0; o2 < 16; ++o2)
            u[o2] = pack2bf(gelu_f(acc[2 * o2][px]), gelu_f(acc[2 * o2 + 1][px]));
        uint4* dst = (uint4*)(op + px * 32);
#pragma unroll
        for (int q = 0; q < 4; ++q)
            dst[q] = make_uint4(u[4 * q], u[4 * q + 1], u[4 * q + 2], u[4 * q + 3]);
    }
}

// ---------------------------------------------------------------------------
// K6: MFMA 32->32 conv. NHWC bf16 in/out. BN+bias folded; optional residual
// (added after BN, before gelu). Tile 16x64 px, halo in LDS (80 B/px pad),
// weights reordered [tap][cout][cin] bf16 in LDS.
// mfma_f32_16x16x32_bf16: A=W[cout][cin] (row=l&15,k=(l>>4)*8+j),
// B=pixels (col=l&15,k likewise), D: col(px)=l&15, row(cout)=(l>>4)*4+reg.
// ---------------------------------------------------------------------------
#define TH 16
#define TW 64
#define HALO_H 18
#define HALO_W 66
#define CSTR 40   // padded ushort stride per pixel (80 B: 16B-aligned, banks spread)

template <bool HAS_RES>
__global__ __launch_bounds__(512, 2) void conv32_mfma(
    const ushort* __restrict__ in, const ushort* __restrict__ res,
    const float* __restrict__ wgt, const float* __restrict__ bias,
    const float* __restrict__ bn_g, const float* __restrict__ bn_bt,
    ushort* __restrict__ out)
{
    __shared__ ushort halo[HALO_H * HALO_W * CSTR];   // 95040 B
    __shared__ ushort wl[9 * 32 * CSTR];              // 23040 B
    __shared__ float s_scale[32], s_shift[32];

    const int tid = threadIdx.x;
    const int b  = blockIdx.z;
    const int h0 = blockIdx.y * TH;
    const int w0 = blockIdx.x * TW;

    // weight reorder: wl[tap][co][ci] = bf16(wgt[co*288 + ci*9 + tap])
    for (int i = tid; i < 9 * 32 * 32; i += 512) {
        int tap = i >> 10, rem = i & 1023;
        int co = rem >> 5, ci = rem & 31;
        wl[tap * 32 * CSTR + co * CSTR + ci] = f2bf(wgt[co * 288 + ci * 9 + tap]);
    }
    if (tid < 32) {
        float sg = bn_g[tid] * 0.9999950000375f;   // g*(1+1e-5)^-0.5
        s_scale[tid] = sg;
        s_shift[tid] = bias[tid] * sg + bn_bt[tid];
    }

    // stage halo (zero-filled OOB); 16B chunks, coalesced NHWC reads
    const ushort* inb = in + (long)b * HWPX * 32;
    for (int i = tid; i < HALO_H * HALO_W * 4; i += 512) {
        int row = i / (HALO_W * 4);
        int rem = i - row * (HALO_W * 4);
        int px = rem >> 2, q = rem & 3;
        int gh = h0 + row - 1, gw = w0 + px - 1;
        uint4 v = make_uint4(0u, 0u, 0u, 0u);
        if (gh >= 0 && gh < HGT && gw >= 0 && gw < WID)
            v = *(const uint4*)(inb + ((long)gh * WID + gw) * 32 + q * 8);
        *(uint4*)(&halo[(row * HALO_W + px) * CSTR + q * 8]) = v;
    }
    __syncthreads();

    const int lane = tid & 63, wid = tid >> 6;
    const int l15 = lane & 15, kg = lane >> 4;
    const int r_base = wid * 2;

    f32x4 acc[8][2];
#pragma unroll
    for (int f = 0; f < 8; ++f)
#pragma unroll
        for (int cf = 0; cf < 2; ++cf)
            acc[f][cf] = (f32x4){0.f, 0.f, 0.f, 0.f};

#pragma unroll
    for (int tap = 0; tap < 9; ++tap) {
        const int dh = tap / 3, dw = tap - dh * 3;
        const bf16x8 a0 = *(const bf16x8*)(&wl[tap * 32 * CSTR + l15 * CSTR + kg * 8]);
        const bf16x8 a1 = *(const bf16x8*)(&wl[tap * 32 * CSTR + (16 + l15) * CSTR + kg * 8]);
#pragma unroll
        for (int f = 0; f < 8; ++f) {
            const int r  = r_base + (f >> 2);
            const int c0 = (f & 3) * 16;
            const bf16x8 bf = *(const bf16x8*)(
                &halo[((r + dh) * HALO_W + (c0 + dw + l15)) * CSTR + kg * 8]);
            acc[f][0] = __builtin_amdgcn_mfma_f32_16x16x32_bf16(a0, bf, acc[f][0], 0, 0, 0);
            acc[f][1] = __builtin_amdgcn_mfma_f32_16x16x32_bf16(a1, bf, acc[f][1], 0, 0, 0);
        }
    }

    // epilogue: scale/shift (+res) + gelu -> bf16 NHWC
#pragma unroll
    for (int f = 0; f < 8; ++f) {
        const int r  = r_base + (f >> 2);
        const int c0 = (f & 3) * 16;
        const long gpx = (long)b * HWPX + (long)(h0 + r) * WID + (w0 + c0 + l15);
#pragma unroll
        for (int cf = 0; cf < 2; ++cf) {
            const int co0 = cf * 16 + kg * 4;
            const float4 sc = *(const float4*)(&s_scale[co0]);
            const float4 sh = *(const float4*)(&s_shift[co0]);
            float v0 = acc[f][cf][0] * sc.x + sh.x;
            float v1 = acc[f][cf][1] * sc.y + sh.y;
            float v2 = acc[f][cf][2] * sc.z + sh.z;
            float v3 = acc[f][cf][3] * sc.w + sh.w;
            if (HAS_RES) {
                const uint2 rv = *(const uint2*)(res + gpx * 32 + co0);
                v0 += bf2f_lo(rv.x); v1 += bf2f_hi(rv.x);
                v2 += bf2f_lo(rv.y); v3 += bf2f_hi(rv.y);
            }
            uint2 o;
            o.x = pack2bf(gelu_f(v0), gelu_f(v1));
            o.y = pack2bf(gelu_f(v2), gelu_f(v3));
            *(uint2*)(out + gpx * 32 + co0) = o;
        }
    }
}

// ---------------------------------------------------------------------------
// K7: 32->3 conv (NHWC bf16 -> comb slots 4..6 fp32), no BN/gelu. 1 px/thread.
// ---------------------------------------------------------------------------
__global__ __launch_bounds__(256) void conv_out3_kernel(
    const ushort* __restrict__ in, const float* __restrict__ wgt,
    const float* __restrict__ bias, float* __restrict__ comb)
{
    const int p = blockIdx.x * 256 + threadIdx.x;
    const int b = blockIdx.y;
    const int hh = p / WID, ww = p - hh * WID;
    float acc[3] = {bias[0], bias[1], bias[2]};

#pragma unroll
    for (int tap = 0; tap < 9; ++tap) {
        const int dh = tap / 3, dw = tap - dh * 3;
        const int gh = hh + dh - 1, gw = ww + dw - 1;
        if (gh < 0 || gh >= HGT || gw < 0 || gw >= WID) continue;
        const uint4* xp = (const uint4*)(in + ((long)b * HWPX + gh * WID + gw) * 32);
        float xx[32];
#pragma unroll
        for (int q = 0; q < 4; ++q) {
            uint4 v = xp[q];
            xx[q * 8 + 0] = bf2f_lo(v.x); xx[q * 8 + 1] = bf2f_hi(v.x);
            xx[q * 8 + 2] = bf2f_lo(v.y); xx[q * 8 + 3] = bf2f_hi(v.y);
            xx[q * 8 + 4] = bf2f_lo(v.z); xx[q * 8 + 5] = bf2f_hi(v.z);
            xx[q * 8 + 6] = bf2f_lo(v.w); xx[q * 8 + 7] = bf2f_hi(v.w);
        }
#pragma unroll
        for (int o = 0; o < 3; ++o)
#pragma unroll
            for (int ci = 0; ci < 32; ++ci)
                acc[o] += xx[ci] * wgt[o * 288 + ci * 9 + tap];
    }
    float4 r4; r4.x = acc[0]; r4.y = acc[1]; r4.z = acc[2]; r4.w = 0.f;
    *(float4*)(comb + ((long)b * HWPX + p) * 8 + 4) = r4;
}

// ---------------------------------------------------------------------------
// K8: 6->32 conv (comb fp32 [px][8] -> act NHWC bf16), gelu. 1 px/thread.
// slots {0,1,2} = fused (w ci 0..2), slots {4,5,6} = proc (w ci 3..5).
// ---------------------------------------------------------------------------
__global__ __launch_bounds__(256) void conv_in6_kernel(
    const float* __restrict__ comb, const float* __restrict__ wgt,
    const float* __restrict__ bias, ushort* __restrict__ out)
{
    const int p = blockIdx.x * 256 + threadIdx.x;
    const int b = blockIdx.y;
    const int hh = p / WID, ww = p - hh * WID;

    float acc[32];
#pragma unroll
    for (int o = 0; o < 32; ++o) acc[o] = bias[o];

#pragma unroll
    for (int tap = 0; tap < 9; ++tap) {
        const int dh = tap / 3, dw = tap - dh * 3;
        const int gh = hh + dh - 1, gw = ww + dw - 1;
        if (gh < 0 || gh >= HGT || gw < 0 || gw >= WID) continue;
        const float4* cp = (const float4*)(comb + ((long)b * HWPX + gh * WID + gw) * 8);
        const float4 qa = cp[0], qb = cp[1];
        const float xs[6] = {qa.x, qa.y, qa.z, qb.x, qb.y, qb.z};
#pragma unroll
        for (int o = 0; o < 32; ++o) {
            const float* wv = wgt + o * 54 + tap;   // uniform -> s_load
            acc[o] += xs[0] * wv[0]  + xs[1] * wv[9]  + xs[2] * wv[18]
                    + xs[3] * wv[27] + xs[4] * wv[36] + xs[5] * wv[45];
        }
    }

    ushort* op = out + ((long)b * HWPX + p) * 32;
    uint u[16];
#pragma unroll
    for (int o2 = 0; o2 < 16; ++o2)
        u[o2] = pack2bf(gelu_f(acc[2 * o2]), gelu_f(acc[2 * o2 + 1]));
    uint4* dst = (uint4*)op;
#pragma unroll
    for (int q = 0; q < 4; ++q)
        dst[q] = make_uint4(u[4 * q], u[4 * q + 1], u[4 * q + 2], u[4 * q + 3]);
}

// ---------------------------------------------------------------------------
// K9: final 32->3 conv (NHWC bf16) + img -> d_out fp32 NCHW. 1 px/thread.
// ---------------------------------------------------------------------------
__global__ __launch_bounds__(256) void conv_final_kernel(
    const ushort* __restrict__ in, const float* __restrict__ wgt,
    const float* __restrict__ bias, const float* __restrict__ img,
    float* __restrict__ outp)
{
    const int p = blockIdx.x * 256 + threadIdx.x;
    const int b = blockIdx.y;
    const int hh = p / WID, ww = p - hh * WID;
    float acc[3] = {bias[0], bias[1], bias[2]};

#pragma unroll
    for (int tap = 0; tap < 9; ++tap) {
        const int dh = tap / 3, dw = tap - dh * 3;
        const int gh = hh + dh - 1, gw = ww + dw - 1;
        if (gh < 0 || gh >= HGT || gw < 0 || gw >= WID) continue;
        const uint4* xp = (const uint4*)(in + ((long)b * HWPX + gh * WID + gw) * 32);
        float xx[32];
#pragma unroll
        for (int q = 0; q < 4; ++q) {
            uint4 v = xp[q];
            xx[q * 8 + 0] = bf2f_lo(v.x); xx[q * 8 + 1] = bf2f_hi(v.x);
            xx[q * 8 + 2] = bf2f_lo(v.y); xx[q * 8 + 3] = bf2f_hi(v.y);
            xx[q * 8 + 4] = bf2f_lo(v.z); xx[q * 8 + 5] = bf2f_hi(v.z);
            xx[q * 8 + 6] = bf2f_lo(v.w); xx[q * 8 + 7] = bf2f_hi(v.w);
        }
#pragma unroll
        for (int o = 0; o < 3; ++o)
#pragma unroll
            for (int ci = 0; ci < 32; ++ci)
                acc[o] += xx[ci] * wgt[o * 288 + ci * 9 + tap];
    }
#pragma unroll
    for (int o = 0; o < 3; ++o)
        outp[(long)(b * 3 + o) * HWPX + p] = acc[o] + img[(long)(b * 3 + o) * HWPX + p];
}

// ---------------------------------------------------------------------------
extern "C" void kernel_launch(void* const* d_in, const int* in_sizes, int n_in,
                              void* d_out, int out_size, void* d_ws, size_t ws_size,
                              hipStream_t stream)
{
    const int*   tokens  = (const int*)d_in[0];
    const float* img     = (const float*)d_in[1];
    const float* recon   = (const float*)d_in[2];
    const float* emb     = (const float*)d_in[3];
    const float* agg_w1  = (const float*)d_in[4];
    const float* agg_b1  = (const float*)d_in[5];
    const float* agg_w2  = (const float*)d_in[6];
    const float* agg_b2  = (const float*)d_in[7];
    const float* lut_w1  = (const float*)d_in[8];
    const float* lut_b1  = (const float*)d_in[9];
    const float* lut_w2  = (const float*)d_in[10];
    const float* lut_b2  = (const float*)d_in[11];
    const float* wg_w1   = (const float*)d_in[12];
    const float* wg_b1   = (const float*)d_in[13];
    const float* wg_w2   = (const float*)d_in[14];
    const float* wg_b2   = (const float*)d_in[15];
    const float* rp_cin_w = (const float*)d_in[16];
    const float* rp_cin_b = (const float*)d_in[17];
    const float* rp_rbA_w = (const float*)d_in[18];
    const float* rp_rbA_b = (const float*)d_in[19];
    const float* rp_rbA_g = (const float*)d_in[20];
    const float* rp_rbA_bt= (const float*)d_in[21];
    const float* rp_rbB_w = (const float*)d_in[22];
    const float* rp_rbB_b = (const float*)d_in[23];
    const float* rp_rbB_g = (const float*)d_in[24];
    const float* rp_rbB_bt= (const float*)d_in[25];
    const float* rp_cout_w= (const float*)d_in[26];
    const float* rp_cout_b= (const float*)d_in[27];
    const float* fu_cin_w = (const float*)d_in[28];
    const float* fu_cin_b = (const float*)d_in[29];
    const float* fu_rbA_w = (const float*)d_in[30];
    const float* fu_rbA_b = (const float*)d_in[31];
    const float* fu_rbA_g = (const float*)d_in[32];
    const float* fu_rbA_bt= (const float*)d_in[33];
    const float* fu_rbB_w = (const float*)d_in[34];
    const float* fu_rbB_b = (const float*)d_in[35];
    const float* fu_rbB_g = (const float*)d_in[36];
    const float* fu_rbB_bt= (const float*)d_in[37];
    const float* fu_cout_w= (const float*)d_in[38];
    const float* fu_cout_b= (const float*)d_in[39];

    float* ws = (float*)d_ws;
    float*  h3      = ws;                      // 1024
    float*  lwv     = ws + 1024;               // 32
    float*  partial = ws + 2048;               // 32768
    float*  lp      = ws + 40960;              // 3449952
    float*  clut    = ws + 3491840;            // 431244
    float*  comb    = ws + 3932160;            // 4718592  ([px][8] fp32)
    ushort* act0    = (ushort*)(ws + 8650752); // 18874368 ushorts
    ushort* act1    = (ushort*)(ws + 18087936);
    ushort* act2    = (ushort*)(ws + 27525120);
    float*  outp    = (float*)d_out;

    // token head
    emb_partial_kernel<<<dim3(32, BB), dim3(256), 0, stream>>>(tokens, emb, partial);
    mlp_head_kernel<<<dim3(BB), dim3(256), 0, stream>>>(
        partial, agg_w1, agg_b1, agg_w2, agg_b2,
        lut_w1, lut_b1, wg_w1, wg_b1, wg_w2, wg_b2, h3, lwv);

    // LUT path
    lut_gemm_kernel<<<dim3((NCOL / 4 + 255) / 256), dim3(256), 0, stream>>>(
        h3, lut_w2, lut_b2, lp);
    combine_kernel<<<dim3((G3 + 255) / 256, BB), dim3(256), 0, stream>>>(lp, lwv, clut);
    applylut_kernel<<<dim3(HWPX / 256, BB), dim3(256), 0, stream>>>(clut, recon, comb);

    const dim3 g1(HWPX / 256, BB), g2(HWPX / 512, BB), blk(256);
    const dim3 gm(WID / TW, HGT / TH, BB), bm(512);

    // proc branch: img -> act0 -> act1 -> act2 -> comb[4..6]
    conv_in3_kernel<<<g2, blk, 0, stream>>>(img, rp_cin_w, rp_cin_b, act0);
    conv32_mfma<false><<<gm, bm, 0, stream>>>(
        act0, nullptr, rp_rbA_w, rp_rbA_b, rp_rbA_g, rp_rbA_bt, act1);
    conv32_mfma<true><<<gm, bm, 0, stream>>>(
        act1, act0, rp_rbB_w, rp_rbB_b, rp_rbB_g, rp_rbB_bt, act2);
    conv_out3_kernel<<<g1, blk, 0, stream>>>(act2, rp_cout_w, rp_cout_b, comb);

    // fuse branch: comb -> act0 -> act1 -> act2 -> d_out (+img)
    conv_in6_kernel<<<g1, blk, 0, stream>>>(comb, fu_cin_w, fu_cin_b, act0);
    conv32_mfma<false><<<gm, bm, 0, stream>>>(
        act0, nullptr, fu_rbA_w, fu_rbA_b, fu_rbA_g, fu_rbA_bt, act1);
    conv32_mfma<true><<<gm, bm, 0, stream>>>(
        act1, act0, fu_rbB_w, fu_rbB_b, fu_rbB_g, fu_rbB_bt, act2);
    conv_final_kernel<<<g1, blk, 0, stream>>>(act2, fu_cout_w, fu_cout_b, img, outp);
}

// Round 5
// 587.559 us; speedup vs baseline: 4.0107x; 1.0636x over previous
//
#include <hip/hip_runtime.h>
#include <hip/hip_bf16.h>
#include <math.h>

// Problem constants
#define BB    4
#define TT    1024
#define EE    256
#define HIDD  256
#define LLUT  8
#define HGT   384
#define WID   384
#define HWPX  147456      // 384*384
#define GSZ   33
#define G3    35937       // 33^3
#define NCOL  862488      // L*3*G3

typedef __attribute__((ext_vector_type(8))) short bf16x8;   // 8 bf16 = 4 VGPRs
typedef __attribute__((ext_vector_type(4))) float f32x4;

// fast gelu (tanh form): max abs dev from exact erf-gelu ~1e-3, threshold 2e-2
__device__ __forceinline__ float gelu_f(float x) {
    float s = 1.5957691216057308f * x * (1.0f + 0.044715f * x * x);
    float e = __expf(s);
    return x - x / (e + 1.0f);   // x*sigmoid(s); safe at +-inf
}

__device__ __forceinline__ ushort f2bf(float x) {
    uint u = __float_as_uint(x);
    return (ushort)((u + 0x7FFFu + ((u >> 16) & 1u)) >> 16);   // RNE
}
__device__ __forceinline__ uint pack2bf(float a, float b) {
    return (uint)f2bf(a) | ((uint)f2bf(b) << 16);
}
__device__ __forceinline__ float bf2f_lo(uint u) { return __uint_as_float(u << 16); }
__device__ __forceinline__ float bf2f_hi(uint u) { return __uint_as_float(u & 0xFFFF0000u); }

// ---------------------------------------------------------------------------
// K0: embedding-mean partial sums. grid (32, B): 32 tokens per block.
// ---------------------------------------------------------------------------
__global__ __launch_bounds__(256) void emb_partial_kernel(
    const int* __restrict__ tokens, const float* __restrict__ emb,
    float* __restrict__ partial)
{
    const int s = blockIdx.x, b = blockIdx.y, tid = threadIdx.x;
    const int* tok = tokens + b * TT + s * 32;
    float acc = 0.f;
#pragma unroll 8
    for (int t = 0; t < 32; ++t) acc += emb[tok[t] * EE + tid];
    partial[(b * 32 + s) * EE + tid] = acc;
}

// ---------------------------------------------------------------------------
// K1: fused token head. One block per batch b.
// ---------------------------------------------------------------------------
__global__ __launch_bounds__(256) void mlp_head_kernel(
    const float* __restrict__ partial,
    const float* __restrict__ aw1, const float* __restrict__ ab1,
    const float* __restrict__ aw2, const float* __restrict__ ab2,
    const float* __restrict__ lw1, const float* __restrict__ lb1,
    const float* __restrict__ gw1, const float* __restrict__ gb1,
    const float* __restrict__ gw2, const float* __restrict__ gb2,
    float* __restrict__ h3_out, float* __restrict__ lw_out)
{
    const int b = blockIdx.x;
    const int tid = threadIdx.x;
    __shared__ float tf[256], h1[256], tf2s[256], h4[64], lg[8];

    float acc = 0.f;
#pragma unroll
    for (int s = 0; s < 32; ++s) acc += partial[(b * 32 + s) * EE + tid];
    tf[tid] = acc * (1.0f / TT);
    __syncthreads();

    {   float s = ab1[tid];
        for (int k = 0; k < EE; ++k) s += tf[k] * aw1[k * HIDD + tid];
        h1[tid] = gelu_f(s);
    }
    __syncthreads();
    {   float s = ab2[tid];
        for (int k = 0; k < HIDD; ++k) s += h1[k] * aw2[k * HIDD + tid];
        tf2s[tid] = s;
    }
    __syncthreads();
    {   float s = lb1[tid];
        for (int k = 0; k < HIDD; ++k) s += tf2s[k] * lw1[k * HIDD + tid];
        h3_out[b * HIDD + tid] = gelu_f(s);
    }
    if (tid < 64) {
        float s = gb1[tid];
        for (int k = 0; k < HIDD; ++k) s += tf2s[k] * gw1[k * 64 + tid];
        h4[tid] = gelu_f(s);
    }
    __syncthreads();
    if (tid < LLUT) {
        float s = gb2[tid];
        for (int k = 0; k < 64; ++k) s += h4[k] * gw2[k * LLUT + tid];
        lg[tid] = s;
    }
    __syncthreads();
    if (tid == 0) {
        float m = lg[0];
        for (int i = 1; i < LLUT; ++i) m = fmaxf(m, lg[i]);
        float ssum = 0.f, ex[LLUT];
        for (int i = 0; i < LLUT; ++i) { ex[i] = expf(lg[i] - m); ssum += ex[i]; }
        for (int i = 0; i < LLUT; ++i) lw_out[b * LLUT + i] = ex[i] / ssum;
    }
}

// ---------------------------------------------------------------------------
// K2: big GEMM. Streams 883 MB of w2 once; HBM-bound floor ~140 us.
// ---------------------------------------------------------------------------
__global__ __launch_bounds__(256) void lut_gemm_kernel(
    const float* __restrict__ h3, const float* __restrict__ w2,
    const float* __restrict__ b2, float* __restrict__ lp)
{
    __shared__ float h[BB * HIDD];
    const int tid = threadIdx.x;
    for (int i = tid; i < BB * HIDD; i += 256) h[i] = h3[i];
    __syncthreads();

    const long col = ((long)blockIdx.x * 256 + tid) * 4;
    if (col >= NCOL) return;

    const float4 bias = *(const float4*)(b2 + col);
    float4 a0 = bias, a1 = bias, a2 = bias, a3 = bias;
    const float* wp = w2 + col;
#pragma unroll 4
    for (int k = 0; k < HIDD; ++k) {
        float4 w = *(const float4*)(wp + (long)k * NCOL);
        float h0 = h[k], h1v = h[HIDD + k], h2 = h[2 * HIDD + k], h3v = h[3 * HIDD + k];
        a0.x += h0 * w.x;  a0.y += h0 * w.y;  a0.z += h0 * w.z;  a0.w += h0 * w.w;
        a1.x += h1v * w.x; a1.y += h1v * w.y; a1.z += h1v * w.z; a1.w += h1v * w.w;
        a2.x += h2 * w.x;  a2.y += h2 * w.y;  a2.z += h2 * w.z;  a2.w += h2 * w.w;
        a3.x += h3v * w.x; a3.y += h3v * w.y; a3.z += h3v * w.z; a3.w += h3v * w.w;
    }
    *(float4*)(lp + 0L * NCOL + col) = a0;
    *(float4*)(lp + 1L * NCOL + col) = a1;
    *(float4*)(lp + 2L * NCOL + col) = a2;
    *(float4*)(lp + 3L * NCOL + col) = a3;
}

// ---------------------------------------------------------------------------
// K3: combine 8 LUTs with softmax weights -> one 3-channel LUT per batch.
// ---------------------------------------------------------------------------
__global__ __launch_bounds__(256) void combine_kernel(
    const float* __restrict__ lp, const float* __restrict__ lwv,
    float* __restrict__ clut)
{
    const int v = blockIdx.x * 256 + threadIdx.x;
    const int b = blockIdx.y;
    if (v >= G3) return;
    float w[LLUT];
#pragma unroll
    for (int l = 0; l < LLUT; ++l) w[l] = lwv[b * LLUT + l];
#pragma unroll
    for (int c = 0; c < 3; ++c) {
        float s = 0.f;
#pragma unroll
        for (int l = 0; l < LLUT; ++l)
            s += w[l] * lp[(long)b * NCOL + (long)(l * 3 + c) * G3 + v];
        clut[(long)(b * 3 + c) * G3 + v] = s;
    }
}

// ---------------------------------------------------------------------------
// K4: trilinear LUT apply -> comb slots 0..2 (fp32, [px][8] layout)
// ---------------------------------------------------------------------------
__global__ __launch_bounds__(256) void applylut_kernel(
    const float* __restrict__ clut, const float* __restrict__ recon,
    float* __restrict__ comb)
{
    const int p = blockIdx.x * 256 + threadIdx.x;
    const int b = blockIdx.y;
    const float* rc = recon + (long)b * 3 * HWPX;
    float cr = fminf(fmaxf(rc[p] * 32.f, 0.f), 32.f);
    float cg = fminf(fmaxf(rc[HWPX + p] * 32.f, 0.f), 32.f);
    float cb = fminf(fmaxf(rc[2 * HWPX + p] * 32.f, 0.f), 32.f);
    float fr = fminf(floorf(cr), 31.f);
    float fg = fminf(floorf(cg), 31.f);
    float fb = fminf(floorf(cb), 31.f);
    float tr = cr - fr, tg = cg - fg, tb_ = cb - fb;
    int idx = (((int)fr * GSZ + (int)fg) * GSZ + (int)fb);
    float c[3];
#pragma unroll
    for (int ch = 0; ch < 3; ++ch) {
        const float* lut = clut + (long)(b * 3 + ch) * G3;
        float v000 = lut[idx],                  v001 = lut[idx + 1];
        float v010 = lut[idx + GSZ],            v011 = lut[idx + GSZ + 1];
        float v100 = lut[idx + GSZ * GSZ],      v101 = lut[idx + GSZ * GSZ + 1];
        float v110 = lut[idx + GSZ * GSZ + GSZ], v111 = lut[idx + GSZ * GSZ + GSZ + 1];
        float c00 = v000 + (v001 - v000) * tb_;
        float c01 = v010 + (v011 - v010) * tb_;
        float c10 = v100 + (v101 - v100) * tb_;
        float c11 = v110 + (v111 - v110) * tb_;
        float c0 = c00 + (c01 - c00) * tg;
        float c1 = c10 + (c11 - c10) * tg;
        c[ch] = c0 + (c1 - c0) * tr;
    }
    float4 r4; r4.x = c[0]; r4.y = c[1]; r4.z = c[2]; r4.w = 0.f;
    *(float4*)(comb + ((long)b * HWPX + p) * 8) = r4;
}

// ---------------------------------------------------------------------------
// K5: 3->32 conv (img fp32 NCHW -> act NHWC bf16), gelu. 2 px/thread.
// Weights via uniform indices -> SGPRs.
// ---------------------------------------------------------------------------
__global__ __launch_bounds__(256) void conv_in3_kernel(
    const float* __restrict__ img, const float* __restrict__ wgt,
    const float* __restrict__ bias, ushort* __restrict__ out)
{
    const int tid = threadIdx.x;
    const int p0 = (blockIdx.x * 256 + tid) * 2;
    const int b = blockIdx.y;
    const int hh = p0 / WID, ww = p0 - hh * WID;

    float acc[32][2];
#pragma unroll
    for (int o = 0; o < 32; ++o) { float bv = bias[o]; acc[o][0] = bv; acc[o][1] = bv; }

    const bool wlo = (ww > 0), whi = (ww + 2 < WID);
#pragma unroll
    for (int ci = 0; ci < 3; ++ci) {
        const float* ip = img + (long)(b * 3 + ci) * HWPX;
        float x[3][4];
#pragma unroll
        for (int dh = 0; dh < 3; ++dh) {
            const int hs = hh + dh - 1;
            const bool hok = (hs >= 0) && (hs < HGT);
            const float* rp_ = ip + hs * WID + ww;
            x[dh][0] = (hok && wlo) ? rp_[-1] : 0.f;
            x[dh][1] = hok ? rp_[0] : 0.f;
            x[dh][2] = hok ? rp_[1] : 0.f;
            x[dh][3] = (hok && whi) ? rp_[2] : 0.f;
        }
#pragma unroll
        for (int o = 0; o < 32; ++o) {
            const float* wv = wgt + o * 27 + ci * 9;   // uniform -> s_load
#pragma unroll
            for (int dh = 0; dh < 3; ++dh)
#pragma unroll
                for (int dw = 0; dw < 3; ++dw) {
                    const float w = wv[dh * 3 + dw];
                    acc[o][0] += x[dh][dw]     * w;
                    acc[o][1] += x[dh][dw + 1] * w;
                }
        }
    }

    ushort* op = out + ((long)b * HWPX + p0) * 32;
#pragma unroll
    for (int px = 0; px < 2; ++px) {
        uint u[16];
#pragma unroll
        for (int o2 = 0; o2 < 16; ++o2)
            u[o2] = pack2bf(gelu_f(acc[2 * o2][px]), gelu_f(acc[2 * o2 + 1][px]));
        uint4* dst = (uint4*)(op + px * 32);
#pragma unroll
        for (int q = 0; q < 4; ++q)
            dst[q] = make_uint4(u[4 * q], u[4 * q + 1], u[4 * q + 2], u[4 * q + 3]);
    }
}

// ---------------------------------------------------------------------------
// K6 v2: MFMA 32->32 conv. NHWC bf16 in/out. BN+bias folded; optional
// residual (added after BN, before gelu).
// Tile 8 rows x 64 px, 8 waves (1 row/wave). Halo 10x66 px in LDS, pixel
// stride CSTR=40 ushort (80 B = 5 bank-quads -> (5*px+kg)%8 uniform,
// conflict-free b128). A-fragments packed lane-linear: 1 KB per (tap,half).
// LDS total ~71.3 KB -> 2 blocks/CU: halo staging of block n+1 overlaps
// MFMA of block n (round-3 version was 118 KB -> 1 block/CU, serialized).
// mfma_f32_16x16x32_bf16: A=W[cout][cin] (row=l&15,k=(l>>4)*8+j),
// B=pixels (col=l&15,k likewise), D: col(px)=l&15, row(cout)=(l>>4)*4+reg.
// ---------------------------------------------------------------------------
#define TH2 8
#define TW2 64
#define HALO_H2 10
#define HALO_W2 66
#define CSTR 40   // padded ushort stride per pixel (80 B)

template <bool HAS_RES>
__global__ __launch_bounds__(512, 4) void conv32_mfma(
    const ushort* __restrict__ in, const ushort* __restrict__ res,
    const float* __restrict__ wgt, const float* __restrict__ bias,
    const float* __restrict__ bn_g, const float* __restrict__ bn_bt,
    ushort* __restrict__ out)
{
    __shared__ ushort halo[HALO_H2 * HALO_W2 * CSTR];   // 52800 B
    __shared__ ushort wlA[9 * 2 * 64 * 8];              // 18432 B, lane-linear
    __shared__ float s_scale[32], s_shift[32];

    const int tid = threadIdx.x;
    const int b  = blockIdx.z;
    const int h0 = blockIdx.y * TH2;
    const int w0 = blockIdx.x * TW2;

    // pack A-frags: wlA[((tap*2+half)*64 + lane)*8 + j]
    //   = bf16( W[cout = half*16 + (lane&15)][cin = (lane>>4)*8 + j][tap] )
    for (int i = tid; i < 9 * 2 * 64 * 8; i += 512) {
        const int j    = i & 7;
        const int lane = (i >> 3) & 63;
        const int half = (i >> 9) & 1;
        const int tap  = i >> 10;
        const int co = half * 16 + (lane & 15);
        const int ci = (lane >> 4) * 8 + j;
        wlA[i] = f2bf(wgt[co * 288 + ci * 9 + tap]);
    }
    if (tid < 32) {
        float sg = bn_g[tid] * 0.9999950000375f;   // g*(1+1e-5)^-0.5
        s_scale[tid] = sg;
        s_shift[tid] = bias[tid] * sg + bn_bt[tid];
    }

    // stage halo (zero-filled OOB); 16B chunks, coalesced NHWC reads
    const ushort* inb = in + (long)b * HWPX * 32;
    for (int i = tid; i < HALO_H2 * HALO_W2 * 4; i += 512) {
        const int row = i / (HALO_W2 * 4);
        const int rem = i - row * (HALO_W2 * 4);
        const int px = rem >> 2, q = rem & 3;
        const int gh = h0 + row - 1, gw = w0 + px - 1;
        uint4 v = make_uint4(0u, 0u, 0u, 0u);
        if (gh >= 0 && gh < HGT && gw >= 0 && gw < WID)
            v = *(const uint4*)(inb + ((long)gh * WID + gw) * 32 + q * 8);
        *(uint4*)(&halo[(row * HALO_W2 + px) * CSTR + q * 8]) = v;
    }
    __syncthreads();

    const int lane = tid & 63, wid = tid >> 6;
    const int l15 = lane & 15, kg = lane >> 4;
    const int r = wid;                      // one output row per wave

    f32x4 acc[4][2];
#pragma unroll
    for (int f = 0; f < 4; ++f)
#pragma unroll
        for (int cf = 0; cf < 2; ++cf)
            acc[f][cf] = (f32x4){0.f, 0.f, 0.f, 0.f};

#pragma unroll
    for (int tap = 0; tap < 9; ++tap) {
        const int dh = tap / 3, dw = tap - dh * 3;
        const bf16x8 a0 = *(const bf16x8*)(&wlA[((tap * 2 + 0) * 64 + lane) * 8]);
        const bf16x8 a1 = *(const bf16x8*)(&wlA[((tap * 2 + 1) * 64 + lane) * 8]);
#pragma unroll
        for (int f = 0; f < 4; ++f) {
            const int c0 = f * 16;
            const bf16x8 bfv = *(const bf16x8*)(
                &halo[((r + dh) * HALO_W2 + (c0 + dw + l15)) * CSTR + kg * 8]);
            acc[f][0] = __builtin_amdgcn_mfma_f32_16x16x32_bf16(a0, bfv, acc[f][0], 0, 0, 0);
            acc[f][1] = __builtin_amdgcn_mfma_f32_16x16x32_bf16(a1, bfv, acc[f][1], 0, 0, 0);
        }
    }

    // epilogue: scale/shift (+res) + gelu -> bf16 NHWC
#pragma unroll
    for (int f = 0; f < 4; ++f) {
        const int c0 = f * 16;
        const long gpx = (long)b * HWPX + (long)(h0 + r) * WID + (w0 + c0 + l15);
#pragma unroll
        for (int cf = 0; cf < 2; ++cf) {
            const int co0 = cf * 16 + kg * 4;
            const float4 sc = *(const float4*)(&s_scale[co0]);
            const float4 sh = *(const float4*)(&s_shift[co0]);
            float v0 = acc[f][cf][0] * sc.x + sh.x;
            float v1 = acc[f][cf][1] * sc.y + sh.y;
            float v2 = acc[f][cf][2] * sc.z + sh.z;
            float v3 = acc[f][cf][3] * sc.w + sh.w;
            if (HAS_RES) {
                const uint2 rv = *(const uint2*)(res + gpx * 32 + co0);
                v0 += bf2f_lo(rv.x); v1 += bf2f_hi(rv.x);
                v2 += bf2f_lo(rv.y); v3 += bf2f_hi(rv.y);
            }
            uint2 o;
            o.x = pack2bf(gelu_f(v0), gelu_f(v1));
            o.y = pack2bf(gelu_f(v2), gelu_f(v3));
            *(uint2*)(out + gpx * 32 + co0) = o;
        }
    }
}

// ---------------------------------------------------------------------------
// K7: 32->3 conv (NHWC bf16 -> comb slots 4..6 fp32), no BN/gelu. 1 px/thread.
// ---------------------------------------------------------------------------
__global__ __launch_bounds__(256) void conv_out3_kernel(
    const ushort* __restrict__ in, const float* __restrict__ wgt,
    const float* __restrict__ bias, float* __restrict__ comb)
{
    const int p = blockIdx.x * 256 + threadIdx.x;
    const int b = blockIdx.y;
    const int hh = p / WID, ww = p - hh * WID;
    float acc[3] = {bias[0], bias[1], bias[2]};

#pragma unroll
    for (int tap = 0; tap < 9; ++tap) {
        const int dh = tap / 3, dw = tap - dh * 3;
        const int gh = hh + dh - 1, gw = ww + dw - 1;
        if (gh < 0 || gh >= HGT || gw < 0 || gw >= WID) continue;
        const uint4* xp = (const uint4*)(in + ((long)b * HWPX + gh * WID + gw) * 32);
        float xx[32];
#pragma unroll
        for (int q = 0; q < 4; ++q) {
            uint4 v = xp[q];
            xx[q * 8 + 0] = bf2f_lo(v.x); xx[q * 8 + 1] = bf2f_hi(v.x);
            xx[q * 8 + 2] = bf2f_lo(v.y); xx[q * 8 + 3] = bf2f_hi(v.y);
            xx[q * 8 + 4] = bf2f_lo(v.z); xx[q * 8 + 5] = bf2f_hi(v.z);
            xx[q * 8 + 6] = bf2f_lo(v.w); xx[q * 8 + 7] = bf2f_hi(v.w);
        }
#pragma unroll
        for (int o = 0; o < 3; ++o)
#pragma unroll
            for (int ci = 0; ci < 32; ++ci)
                acc[o] += xx[ci] * wgt[o * 288 + ci * 9 + tap];
    }
    float4 r4; r4.x = acc[0]; r4.y = acc[1]; r4.z = acc[2]; r4.w = 0.f;
    *(float4*)(comb + ((long)b * HWPX + p) * 8 + 4) = r4;
}

// ---------------------------------------------------------------------------
// K8: 6->32 conv (comb fp32 [px][8] -> act NHWC bf16), gelu. 1 px/thread.
// slots {0,1,2} = fused (w ci 0..2), slots {4,5,6} = proc (w ci 3..5).
// ---------------------------------------------------------------------------
__global__ __launch_bounds__(256) void conv_in6_kernel(
    const float* __restrict__ comb, const float* __restrict__ wgt,
    const float* __restrict__ bias, ushort* __restrict__ out)
{
    const int p = blockIdx.x * 256 + threadIdx.x;
    const int b = blockIdx.y;
    const int hh = p / WID, ww = p - hh * WID;

    float acc[32];
#pragma unroll
    for (int o = 0; o < 32; ++o) acc[o] = bias[o];

#pragma unroll
    for (int tap = 0; tap < 9; ++tap) {
        const int dh = tap / 3, dw = tap - dh * 3;
        const int gh = hh + dh - 1, gw = ww + dw - 1;
        if (gh < 0 || gh >= HGT || gw < 0 || gw >= WID) continue;
        const float4* cp = (const float4*)(comb + ((long)b * HWPX + gh * WID + gw) * 8);
        const float4 qa = cp[0], qb = cp[1];
        const float xs[6] = {qa.x, qa.y, qa.z, qb.x, qb.y, qb.z};
#pragma unroll
        for (int o = 0; o < 32; ++o) {
            const float* wv = wgt + o * 54 + tap;   // uniform -> s_load
            acc[o] += xs[0] * wv[0]  + xs[1] * wv[9]  + xs[2] * wv[18]
                    + xs[3] * wv[27] + xs[4] * wv[36] + xs[5] * wv[45];
        }
    }

    ushort* op = out + ((long)b * HWPX + p) * 32;
    uint u[16];
#pragma unroll
    for (int o2 = 0; o2 < 16; ++o2)
        u[o2] = pack2bf(gelu_f(acc[2 * o2]), gelu_f(acc[2 * o2 + 1]));
    uint4* dst = (uint4*)op;
#pragma unroll
    for (int q = 0; q < 4; ++q)
        dst[q] = make_uint4(u[4 * q], u[4 * q + 1], u[4 * q + 2], u[4 * q + 3]);
}

// ---------------------------------------------------------------------------
// K9: final 32->3 conv (NHWC bf16) + img -> d_out fp32 NCHW. 1 px/thread.
// ---------------------------------------------------------------------------
__global__ __launch_bounds__(256) void conv_final_kernel(
    const ushort* __restrict__ in, const float* __restrict__ wgt,
    const float* __restrict__ bias, const float* __restrict__ img,
    float* __restrict__ outp)
{
    const int p = blockIdx.x * 256 + threadIdx.x;
    const int b = blockIdx.y;
    const int hh = p / WID, ww = p - hh * WID;
    float acc[3] = {bias[0], bias[1], bias[2]};

#pragma unroll
    for (int tap = 0; tap < 9; ++tap) {
        const int dh = tap / 3, dw = tap - dh * 3;
        const int gh = hh + dh - 1, gw = ww + dw - 1;
        if (gh < 0 || gh >= HGT || gw < 0 || gw >= WID) continue;
        const uint4* xp = (const uint4*)(in + ((long)b * HWPX + gh * WID + gw) * 32);
        float xx[32];
#pragma unroll
        for (int q = 0; q < 4; ++q) {
            uint4 v = xp[q];
            xx[q * 8 + 0] = bf2f_lo(v.x); xx[q * 8 + 1] = bf2f_hi(v.x);
            xx[q * 8 + 2] = bf2f_lo(v.y); xx[q * 8 + 3] = bf2f_hi(v.y);
            xx[q * 8 + 4] = bf2f_lo(v.z); xx[q * 8 + 5] = bf2f_hi(v.z);
            xx[q * 8 + 6] = bf2f_lo(v.w); xx[q * 8 + 7] = bf2f_hi(v.w);
        }
#pragma unroll
        for (int o = 0; o < 3; ++o)
#pragma unroll
            for (int ci = 0; ci < 32; ++ci)
                acc[o] += xx[ci] * wgt[o * 288 + ci * 9 + tap];
    }
#pragma unroll
    for (int o = 0; o < 3; ++o)
        outp[(long)(b * 3 + o) * HWPX + p] = acc[o] + img[(long)(b * 3 + o) * HWPX + p];
}

// ---------------------------------------------------------------------------
extern "C" void kernel_launch(void* const* d_in, const int* in_sizes, int n_in,
                              void* d_out, int out_size, void* d_ws, size_t ws_size,
                              hipStream_t stream)
{
    const int*   tokens  = (const int*)d_in[0];
    const float* img     = (const float*)d_in[1];
    const float* recon   = (const float*)d_in[2];
    const float* emb     = (const float*)d_in[3];
    const float* agg_w1  = (const float*)d_in[4];
    const float* agg_b1  = (const float*)d_in[5];
    const float* agg_w2  = (const float*)d_in[6];
    const float* agg_b2  = (const float*)d_in[7];
    const float* lut_w1  = (const float*)d_in[8];
    const float* lut_b1  = (const float*)d_in[9];
    const float* lut_w2  = (const float*)d_in[10];
    const float* lut_b2  = (const float*)d_in[11];
    const float* wg_w1   = (const float*)d_in[12];
    const float* wg_b1   = (const float*)d_in[13];
    const float* wg_w2   = (const float*)d_in[14];
    const float* wg_b2   = (const float*)d_in[15];
    const float* rp_cin_w = (const float*)d_in[16];
    const float* rp_cin_b = (const float*)d_in[17];
    const float* rp_rbA_w = (const float*)d_in[18];
    const float* rp_rbA_b = (const float*)d_in[19];
    const float* rp_rbA_g = (const float*)d_in[20];
    const float* rp_rbA_bt= (const float*)d_in[21];
    const float* rp_rbB_w = (const float*)d_in[22];
    const float* rp_rbB_b = (const float*)d_in[23];
    const float* rp_rbB_g = (const float*)d_in[24];
    const float* rp_rbB_bt= (const float*)d_in[25];
    const float* rp_cout_w= (const float*)d_in[26];
    const float* rp_cout_b= (const float*)d_in[27];
    const float* fu_cin_w = (const float*)d_in[28];
    const float* fu_cin_b = (const float*)d_in[29];
    const float* fu_rbA_w = (const float*)d_in[30];
    const float* fu_rbA_b = (const float*)d_in[31];
    const float* fu_rbA_g = (const float*)d_in[32];
    const float* fu_rbA_bt= (const float*)d_in[33];
    const float* fu_rbB_w = (const float*)d_in[34];
    const float* fu_rbB_b = (const float*)d_in[35];
    const float* fu_rbB_g = (const float*)d_in[36];
    const float* fu_rbB_bt= (const float*)d_in[37];
    const float* fu_cout_w= (const float*)d_in[38];
    const float* fu_cout_b= (const float*)d_in[39];

    float* ws = (float*)d_ws;
    float*  h3      = ws;                      // 1024
    float*  lwv     = ws + 1024;               // 32
    float*  partial = ws + 2048;               // 32768
    float*  lp      = ws + 40960;              // 3449952
    float*  clut    = ws + 3491840;            // 431244
    float*  comb    = ws + 3932160;            // 4718592  ([px][8] fp32)
    ushort* act0    = (ushort*)(ws + 8650752); // 18874368 ushorts
    ushort* act1    = (ushort*)(ws + 18087936);
    ushort* act2    = (ushort*)(ws + 27525120);
    float*  outp    = (float*)d_out;

    // token head
    emb_partial_kernel<<<dim3(32, BB), dim3(256), 0, stream>>>(tokens, emb, partial);
    mlp_head_kernel<<<dim3(BB), dim3(256), 0, stream>>>(
        partial, agg_w1, agg_b1, agg_w2, agg_b2,
        lut_w1, lut_b1, wg_w1, wg_b1, wg_w2, wg_b2, h3, lwv);

    // LUT path
    lut_gemm_kernel<<<dim3((NCOL / 4 + 255) / 256), dim3(256), 0, stream>>>(
        h3, lut_w2, lut_b2, lp);
    combine_kernel<<<dim3((G3 + 255) / 256, BB), dim3(256), 0, stream>>>(lp, lwv, clut);
    applylut_kernel<<<dim3(HWPX / 256, BB), dim3(256), 0, stream>>>(clut, recon, comb);

    const dim3 g1(HWPX / 256, BB), g2(HWPX / 512, BB), blk(256);
    const dim3 gm(WID / TW2, HGT / TH2, BB), bm(512);

    // proc branch: img -> act0 -> act1 -> act2 -> comb[4..6]
    conv_in3_kernel<<<g2, blk, 0, stream>>>(img, rp_cin_w, rp_cin_b, act0);
    conv32_mfma<false><<<gm, bm, 0, stream>>>(
        act0, nullptr, rp_rbA_w, rp_rbA_b, rp_rbA_g, rp_rbA_bt, act1);
    conv32_mfma<true><<<gm, bm, 0, stream>>>(
        act1, act0, rp_rbB_w, rp_rbB_b, rp_rbB_g, rp_rbB_bt, act2);
    conv_out3_kernel<<<g1, blk, 0, stream>>>(act2, rp_cout_w, rp_cout_b, comb);

    // fuse branch: comb -> act0 -> act1 -> act2 -> d_out (+img)
    conv_in6_kernel<<<g1, blk, 0, stream>>>(comb, fu_cin_w, fu_cin_b, act0);
    conv32_mfma<false><<<gm, bm, 0, stream>>>(
        act0, nullptr, fu_rbA_w, fu_rbA_b, fu_rbA_g, fu_rbA_bt, act1);
    conv32_mfma<true><<<gm, bm, 0, stream>>>(
        act1, act0, fu_rbB_w, fu_rbB_b, fu_rbB_g, fu_rbB_bt, act2);
    conv_final_kernel<<<g1, blk, 0, stream>>>(act2, fu_cout_w, fu_cout_b, img, outp);
}